// Round 4
// baseline (544.245 us; speedup 1.0000x reference)
//
#include <hip/hip_runtime.h>
#include <hip/hip_bf16.h>
#include <stdint.h>
#include <stddef.h>

typedef __attribute__((ext_vector_type(4))) float f32x4;
typedef __attribute__((ext_vector_type(8))) short short8;

#define MROWS 50176   // 256*196

// ---------- helpers ----------

// floor(g/196) for g < 89240
static __device__ __forceinline__ unsigned div196(unsigned g) {
    return (unsigned)(((unsigned long long)g * 85599ull) >> 24);
}

// fp32 -> bf16 round-to-nearest-even (raw bits; transpose kernel only)
static __device__ __forceinline__ unsigned short f2bf(float f) {
    union { float f; unsigned u; } v; v.f = f;
    unsigned r = v.u + 0x7FFFu + ((v.u >> 16) & 1u);
    return (unsigned short)(r >> 16);
}

// fast tanh: tanh(x) = (e^{2x}-1)/(e^{2x}+1)
static __device__ __forceinline__ float tanh_fast(float x) {
    float xc = fminf(fmaxf(x, -9.f), 9.f);
    float e = __builtin_amdgcn_exp2f(xc * 2.885390081777927f); // 2*log2(e)
    return (e - 1.f) * __builtin_amdgcn_rcpf(e + 1.f);
}

// 8x fp32 -> short8 of bf16 (RNE via v_cvt_pk_bf16_f32)
static __device__ __forceinline__ short8 cvt8bf(f32x4 lo, f32x4 hi) {
    union { short8 s; __hip_bfloat162 h[4]; } u;
    u.h[0] = __float22bfloat162_rn(make_float2(lo[0], lo[1]));
    u.h[1] = __float22bfloat162_rn(make_float2(lo[2], lo[3]));
    u.h[2] = __float22bfloat162_rn(make_float2(hi[0], hi[1]));
    u.h[3] = __float22bfloat162_rn(make_float2(hi[2], hi[3]));
    return u.s;
}

// ---------- barrier-free streaming MFMA K-loop: 128x128 tile, K=1024 ----------
// 256 threads = 4 waves (2x2 wave grid, wave tile 64x64). No LDS.
// Each lane loads its MFMA fragments directly from global:
//   A fp32 row-major stride 1024: per m-frag 2x dwordx4 (32B/lane), cvt->bf16
//   B bf16 [N][K] stride 1024: per n-frag 1x dwordx4 (16B/lane), L2-resident
static __device__ __forceinline__ void kloop_stream(
    const float* __restrict__ A,
    const unsigned short* __restrict__ B,
    f32x4 acc[4][4], int tid)
{
    const int lane = tid & 63, w = tid >> 6;
    const int wr = w >> 1, wc = w & 1;
    const int lrow = lane & 15, lk = lane >> 4;

    const float* Ap[4];
    const unsigned short* Bp[4];
    #pragma unroll
    for (int m = 0; m < 4; ++m)
        Ap[m] = A + (size_t)((wr << 6) + (m << 4) + lrow) * 1024 + (lk << 3);
    #pragma unroll
    for (int n = 0; n < 4; ++n)
        Bp[n] = B + (size_t)((wc << 6) + (n << 4) + lrow) * 1024 + (lk << 3);

    f32x4 z = {0.f, 0.f, 0.f, 0.f};
    #pragma unroll
    for (int m = 0; m < 4; ++m)
        #pragma unroll
        for (int n = 0; n < 4; ++n) acc[m][n] = z;

    #pragma unroll 4
    for (int ks = 0; ks < 32; ++ks) {
        short8 af[4], bf[4];
        #pragma unroll
        for (int m = 0; m < 4; ++m) {
            f32x4 lo = *(const f32x4*)(Ap[m] + (ks << 5));
            f32x4 hi = *(const f32x4*)(Ap[m] + (ks << 5) + 4);
            af[m] = cvt8bf(lo, hi);
        }
        #pragma unroll
        for (int n = 0; n < 4; ++n)
            bf[n] = *(const short8*)(Bp[n] + (ks << 5));
        #pragma unroll
        for (int m = 0; m < 4; ++m)
            #pragma unroll
            for (int n = 0; n < 4; ++n)
                acc[m][n] = __builtin_amdgcn_mfma_f32_16x16x32_bf16(af[m], bf[n], acc[m][n], 0, 0, 0);
    }
}

// ---------- big fused kernel: visual_attn + attention + alpha (partial) ----------
// XCD-bijective swizzle (1568 = 8*196): work = (j%8)*196 + j/8, then n4 fastest
// within the chunk -> the 4 A-tile sharers run on the SAME XCD back-to-back,
// so A-tile re-reads hit that XCD's L2.
__global__ __launch_bounds__(256, 3) void attn_alpha_kernel(
    const float* __restrict__ spatial,          // [50176][1024] fp32
    const unsigned short* __restrict__ WvT,     // [512][1024] bf16
    const float* __restrict__ b_v_att,          // [512]
    const float* __restrict__ hidden_attn,      // [256][512]
    const float* __restrict__ W_alpha,          // [512]
    float* __restrict__ alphap)                 // [4][50176]
{
    __shared__ float alpha_s[128];
    const int tid = threadIdx.x;
    const int j = blockIdx.x;
    const int wk = (j & 7) * 196 + (j >> 3);
    const int mt = wk >> 2, n4 = wk & 3;
    const int row0 = mt << 7, col0 = n4 << 7;
    if (tid < 128) alpha_s[tid] = 0.f;
    __syncthreads();

    f32x4 acc[4][4];
    kloop_stream(spatial + (size_t)row0 * 1024, WvT + (size_t)col0 * 1024, acc, tid);

    const int lane = tid & 63, w = tid >> 6;
    const int wr = w >> 1, wc = w & 1;
    const int lrow = lane & 15, lk = lane >> 4;

    const unsigned bb0 = div196((unsigned)row0);
    const unsigned bb1 = div196((unsigned)(row0 + 127));
    float bv[4], wa[4], h0[4], h1[4];
    #pragma unroll
    for (int n = 0; n < 4; ++n) {
        int g = col0 + (wc << 6) + (n << 4) + lrow;
        bv[n] = b_v_att[g];
        wa[n] = W_alpha[g];
        h0[n] = hidden_attn[bb0 * 512 + g];
        h1[n] = hidden_attn[bb1 * 512 + g];
    }
    #pragma unroll
    for (int m = 0; m < 4; ++m) {
        #pragma unroll
        for (int i = 0; i < 4; ++i) {
            int rloc = (wr << 6) + (m << 4) + (lk << 2) + i;
            bool first = (div196((unsigned)(row0 + rloc)) == bb0);
            float s = 0.f;
            #pragma unroll
            for (int n = 0; n < 4; ++n) {
                float v = tanh_fast(acc[m][n][i] + bv[n] + (first ? h0[n] : h1[n]));
                s += v * wa[n];
            }
            #pragma unroll
            for (int off = 1; off < 16; off <<= 1) s += __shfl_xor(s, off);
            if (lrow == 0) atomicAdd(&alpha_s[rloc], s);
        }
    }
    __syncthreads();
    if (tid < 128)
        alphap[(size_t)n4 * MROWS + row0 + tid] = alpha_s[tid];
}

// ---------- small GEMM pair: C = act(A @ BT^T + bias), M=256, K=1024 ----------
struct GemmDesc { const float* A; const unsigned short* BT; const float* bias; float* C; int N; int act; };
struct GemmPair { GemmDesc d[2]; };

__global__ __launch_bounds__(256, 3) void gemm_pair_kernel(GemmPair p)
{
    GemmDesc d = p.d[blockIdx.z];
    const int tid = threadIdx.x;
    const int row0 = blockIdx.x << 7;
    const int col0 = blockIdx.y << 7;
    f32x4 acc[4][4];
    kloop_stream(d.A + (size_t)row0 * 1024, d.BT + (size_t)col0 * 1024, acc, tid);
    const int lane = tid & 63, w = tid >> 6;
    const int wr = w >> 1, wc = w & 1;
    const int lrow = lane & 15, lk = lane >> 4;
    #pragma unroll
    for (int n = 0; n < 4; ++n) {
        int col = col0 + (wc << 6) + (n << 4) + lrow;
        float bs = d.bias[col];
        #pragma unroll
        for (int m = 0; m < 4; ++m) {
            int rbase = row0 + (wr << 6) + (m << 4) + (lk << 2);
            #pragma unroll
            for (int i = 0; i < 4; ++i) {
                float v = acc[m][n][i] + bs;
                if (d.act == 1) v = fmaxf(v, 0.f);
                if (d.act == 2) v = tanh_fast(v);
                d.C[(size_t)(rbase + i) * d.N + col] = v;
            }
        }
    }
}

// ---------- batched W transpose + fp32->bf16: src[K][N] -> dst[N][K] ----------
struct TransDesc { const float* src; unsigned short* dst; int K; int N; };
struct TransArgs { TransDesc d[6]; };

__global__ void transpose_cvt_kernel(TransArgs args) {
    TransDesc d = args.d[blockIdx.y];
    int nt = d.N >> 5;
    int tiles = (d.K >> 5) * nt;
    if ((int)blockIdx.x >= tiles) return;
    int tk = blockIdx.x / nt, tn = blockIdx.x % nt;
    __shared__ unsigned short tile[32][33];
    int tx = threadIdx.x & 31, ty = threadIdx.x >> 5;
    int k0 = tk << 5, n0 = tn << 5;
    #pragma unroll
    for (int j = 0; j < 4; ++j)
        tile[ty + j * 8][tx] = f2bf(d.src[(size_t)(k0 + ty + j * 8) * d.N + n0 + tx]);
    __syncthreads();
    #pragma unroll
    for (int j = 0; j < 4; ++j)
        d.dst[(size_t)(n0 + ty + j * 8) * d.K + k0 + tx] = tile[tx][ty + j * 8];
}

// ---------- sentinel alpha + softmax over 197 ----------
__global__ void softmax_sentinel_kernel(
    const float* __restrict__ alphap,   // [4][50176]
    const float* __restrict__ sen_att, const float* __restrict__ hid_att,
    const float* __restrict__ W_alpha,
    float* __restrict__ att, float* __restrict__ beta)
{
    int b = blockIdx.x, tid = threadIdx.x;   // 256 threads
    __shared__ float al[197];
    __shared__ float red[4];
    if (tid < 196) {
        size_t g = (size_t)b * 196 + tid;
        al[tid] = alphap[g] + alphap[MROWS + g] + alphap[2 * MROWS + g] + alphap[3 * MROWS + g];
    }
    float s = 0.f;
    for (int a = tid; a < 512; a += 256)
        s += tanh_fast(sen_att[b * 512 + a] + hid_att[b * 512 + a]) * W_alpha[a];
    #pragma unroll
    for (int off = 1; off < 64; off <<= 1) s += __shfl_xor(s, off);
    if ((tid & 63) == 0) red[tid >> 6] = s;
    __syncthreads();
    if (tid == 0) al[196] = red[0] + red[1] + red[2] + red[3];
    __syncthreads();
    if (tid < 64) {
        float v[4];
        float mx = -1e30f;
        #pragma unroll
        for (int jj = 0; jj < 4; ++jj) {
            int i = tid + jj * 64;
            v[jj] = (i < 197) ? al[i] : -1e30f;
            mx = fmaxf(mx, v[jj]);
        }
        #pragma unroll
        for (int off = 1; off < 64; off <<= 1) mx = fmaxf(mx, __shfl_xor(mx, off));
        float sm = 0.f;
        #pragma unroll
        for (int jj = 0; jj < 4; ++jj) {
            v[jj] = __builtin_amdgcn_exp2f((v[jj] - mx) * 1.442695040888963f);
            if (tid + jj * 64 >= 197) v[jj] = 0.f;
            sm += v[jj];
        }
        #pragma unroll
        for (int off = 1; off < 64; off <<= 1) sm += __shfl_xor(sm, off);
        float inv = 1.f / sm;
        #pragma unroll
        for (int jj = 0; jj < 4; ++jj) {
            int i = tid + jj * 64;
            if (i < 197) {
                float wv = v[jj] * inv;
                att[b * 197 + i] = wv;
                if (i == 196) beta[b] = wv;
            }
        }
    }
}

// ---------- context: ctxh = sum_p w_p * feat_p + w196*sen + hidden_affine ----------
__global__ __launch_bounds__(256) void context_kernel(
    const float* __restrict__ spatial, const float* __restrict__ sen_aff,
    const float* __restrict__ hid_aff, const float* __restrict__ att,
    float* __restrict__ ctxh)
{
    int b = blockIdx.x, half = blockIdx.y, t = threadIdx.x;  // 256 thr, float2
    __shared__ float wsm[197];
    if (t < 197) wsm[t] = att[b * 197 + t];
    __syncthreads();
    int h2 = (half << 8) + t;
    const float2* sp = (const float2*)(spatial + (size_t)b * 196 * 1024) + h2;
    float ax = 0.f, ay = 0.f;
    #pragma unroll 8
    for (int p = 0; p < 196; ++p) {
        float2 x = sp[(size_t)p * 512];
        ax += wsm[p] * x.x; ay += wsm[p] * x.y;
    }
    float w196 = wsm[196];
    float2 sa = ((const float2*)(sen_aff + (size_t)b * 1024))[h2];
    float2 ha = ((const float2*)(hid_aff + (size_t)b * 1024))[h2];
    ctxh[(size_t)b * 1024 + 2 * h2]     = ax + w196 * sa.x + ha.x;
    ctxh[(size_t)b * 1024 + 2 * h2 + 1] = ay + w196 * sa.y + ha.y;
}

// ---------- launch ----------
extern "C" void kernel_launch(void* const* d_in, const int* in_sizes, int n_in,
                              void* d_out, int out_size, void* d_ws, size_t ws_size,
                              hipStream_t stream)
{
    const float* spatial   = (const float*)d_in[0];
    const float* decoder   = (const float*)d_in[1];
    const float* st        = (const float*)d_in[2];
    const float* W_sen_aff = (const float*)d_in[3];
    const float* b_sen_aff = (const float*)d_in[4];
    const float* W_sen_att = (const float*)d_in[5];
    const float* b_sen_att = (const float*)d_in[6];
    const float* W_h_aff   = (const float*)d_in[7];
    const float* b_h_aff   = (const float*)d_in[8];
    const float* W_h_att   = (const float*)d_in[9];
    const float* b_h_att   = (const float*)d_in[10];
    const float* W_v_att   = (const float*)d_in[11];
    const float* b_v_att   = (const float*)d_in[12];
    const float* W_alpha   = (const float*)d_in[13];
    // d_in[14] = b_alpha: cancels in softmax, unused
    const float* W_ctx     = (const float*)d_in[15];
    const float* b_ctx     = (const float*)d_in[16];

    char* ws = (char*)d_ws;
    size_t off = 0;
    auto alloc = [&](size_t bytes) {
        char* p = ws + off; off += (bytes + 255) & ~(size_t)255; return p;
    };
    unsigned short* WvT  = (unsigned short*)alloc((size_t)512 * 1024 * 2);
    unsigned short* WsaT = (unsigned short*)alloc((size_t)1024 * 1024 * 2);
    unsigned short* WstT = (unsigned short*)alloc((size_t)512 * 1024 * 2);
    unsigned short* WhaT = (unsigned short*)alloc((size_t)1024 * 1024 * 2);
    unsigned short* WhtT = (unsigned short*)alloc((size_t)512 * 1024 * 2);
    unsigned short* WcxT = (unsigned short*)alloc((size_t)1024 * 1024 * 2);
    float* sen_aff = (float*)alloc((size_t)256 * 1024 * 4);
    float* sen_att = (float*)alloc((size_t)256 * 512 * 4);
    float* hid_aff = (float*)alloc((size_t)256 * 1024 * 4);
    float* hid_att = (float*)alloc((size_t)256 * 512 * 4);
    float* alphap  = (float*)alloc((size_t)4 * MROWS * 4);
    float* ctxh    = (float*)alloc((size_t)256 * 1024 * 4);

    float* out_l    = (float*)d_out;              // 256*1024
    float* out_att  = out_l + 256 * 1024;         // 256*197
    float* out_beta = out_att + 256 * 197;        // 256

    TransArgs ta;
    ta.d[0] = { W_v_att,   WvT,  1024, 512  };
    ta.d[1] = { W_sen_aff, WsaT, 1024, 1024 };
    ta.d[2] = { W_sen_att, WstT, 1024, 512  };
    ta.d[3] = { W_h_aff,   WhaT, 1024, 1024 };
    ta.d[4] = { W_h_att,   WhtT, 1024, 512  };
    ta.d[5] = { W_ctx,     WcxT, 1024, 1024 };
    transpose_cvt_kernel<<<dim3(1024, 6), 256, 0, stream>>>(ta);

    GemmPair p1;
    p1.d[0] = { st,      WsaT, b_sen_aff, sen_aff, 1024, 1 };
    p1.d[1] = { decoder, WhaT, b_h_aff,   hid_aff, 1024, 2 };
    gemm_pair_kernel<<<dim3(2, 8, 2), 256, 0, stream>>>(p1);

    GemmPair p2;
    p2.d[0] = { sen_aff, WstT, b_sen_att, sen_att, 512, 0 };
    p2.d[1] = { hid_aff, WhtT, b_h_att,   hid_att, 512, 0 };
    gemm_pair_kernel<<<dim3(2, 4, 2), 256, 0, stream>>>(p2);

    attn_alpha_kernel<<<1568, 256, 0, stream>>>(spatial, WvT, b_v_att, hid_att, W_alpha, alphap);
    softmax_sentinel_kernel<<<256, 256, 0, stream>>>(alphap, sen_att, hid_att, W_alpha, out_att, out_beta);
    context_kernel<<<dim3(256, 2), 256, 0, stream>>>(spatial, sen_aff, hid_aff, out_att, ctxh);

    GemmPair p3;
    p3.d[0] = { ctxh, WcxT, b_ctx, out_l, 1024, 2 };
    p3.d[1] = { ctxh, WcxT, b_ctx, out_l, 1024, 2 };
    gemm_pair_kernel<<<dim3(2, 8, 1), 256, 0, stream>>>(p3);
}

// Round 5
// 217.108 us; speedup vs baseline: 2.5068x; 2.5068x over previous
//
#include <hip/hip_runtime.h>
#include <hip/hip_bf16.h>
#include <stdint.h>
#include <stddef.h>

typedef __attribute__((ext_vector_type(4))) float f32x4;
typedef __attribute__((ext_vector_type(8))) short short8;

#define MROWS 50176   // 256*196

// ---------- helpers ----------

// LDS byte offset for (row, k) in a [rows][32] bf16 tile, 16B-slot XOR swizzle.
static __device__ __forceinline__ int lds_off(int row, int k) {
    int slot = (k >> 3) ^ ((row >> 1) & 3);
    return (row << 6) + (slot << 4) + ((k & 7) << 1);
}

// floor(g/196) for g < 89240
static __device__ __forceinline__ unsigned div196(unsigned g) {
    return (unsigned)(((unsigned long long)g * 85599ull) >> 24);
}

// fp32 -> bf16 RNE (bit-twiddle; only used in the tiny transpose kernel)
static __device__ __forceinline__ unsigned short f2bf(float f) {
    union { float f; unsigned u; } v; v.f = f;
    unsigned r = v.u + 0x7FFFu + ((v.u >> 16) & 1u);
    return (unsigned short)(r >> 16);
}

// 4x fp32 -> 4x bf16 packed in 8B, via v_cvt_pk_bf16_f32 (2 VALU ops)
static __device__ __forceinline__ unsigned long long pack4bf(f32x4 a) {
    union { unsigned long long u; __hip_bfloat162 h[2]; } r;
    r.h[0] = __float22bfloat162_rn(make_float2(a[0], a[1]));
    r.h[1] = __float22bfloat162_rn(make_float2(a[2], a[3]));
    return r.u;
}

// fast tanh: tanh(x) = (e^{2x}-1)/(e^{2x}+1)
static __device__ __forceinline__ float tanh_fast(float x) {
    float xc = fminf(fmaxf(x, -9.f), 9.f);
    float e = __builtin_amdgcn_exp2f(xc * 2.885390081777927f); // 2*log2(e)
    return (e - 1.f) * __builtin_amdgcn_rcpf(e + 1.f);
}

static __device__ __forceinline__ void gload_lds16(const void* g, void* l) {
    __builtin_amdgcn_global_load_lds(
        (const __attribute__((address_space(1))) unsigned int*)g,
        (__attribute__((address_space(3))) unsigned int*)l, 16, 0, 0);
}

// ---------- double-buffered MFMA K-loop: 128x128 tile, K=1024, BK=32 ----------
// 256 threads = 4 waves (2x2 wave grid, wave tile 64x64).
// A: fp32 row-major stride 1024, reg-staged, cvt->bf16 via v_cvt_pk (issue-early
//    / write-late). B: bf16 [N][K] stride 1024 via global_load_lds, XOR swizzle
//    folded into the per-lane global source address.
static __device__ __forceinline__ void kloop_dbuf(
    const float* __restrict__ Abase,
    const unsigned short* __restrict__ Bbase,
    char* sA0, char* sA1, char* sB0, char* sB1,
    f32x4 acc[4][4], int tid)
{
    const int lane = tid & 63, w = tid >> 6;
    const int lrow = lane & 15, lk = lane >> 4;
    const int wr = w >> 1, wc = w & 1;

    // A staging coords: 4x f32x4 per thread
    const float* Ap[4];
    int aoff[4];
    #pragma unroll
    for (int r = 0; r < 4; ++r) {
        int q = tid + (r << 8);
        int ar = q >> 3, kc = (q & 7) << 2;
        Ap[r] = Abase + (size_t)ar * 1024 + kc;
        aoff[r] = lds_off(ar, kc);
    }
    // B staging coords: 2 chunks (1KB each) per wave
    const unsigned short* Bp[2];
    int bdst[2];
    #pragma unroll
    for (int c = 0; c < 2; ++c) {
        int ch = (w << 1) + c;
        int row = (ch << 4) + (lane >> 2);
        int kg = (lane & 3) ^ ((row >> 1) & 3);
        Bp[c] = Bbase + (size_t)row * 1024 + (kg << 3);
        bdst[c] = ch << 10;
    }

    f32x4 z = {0.f, 0.f, 0.f, 0.f};
    #pragma unroll
    for (int m = 0; m < 4; ++m)
        #pragma unroll
        for (int n = 0; n < 4; ++n) acc[m][n] = z;

    // prologue: stage ks=0
    {
        f32x4 a[4];
        #pragma unroll
        for (int r = 0; r < 4; ++r) a[r] = *(const f32x4*)Ap[r];
        #pragma unroll
        for (int c = 0; c < 2; ++c) gload_lds16(Bp[c], sB0 + bdst[c]);
        #pragma unroll
        for (int r = 0; r < 4; ++r)
            *(unsigned long long*)(sA0 + aoff[r]) = pack4bf(a[r]);
    }
    __syncthreads();

    char* sAc = sA0; char* sAn = sA1;
    char* sBc = sB0; char* sBn = sB1;
    for (int ks = 0; ks < 32; ++ks) {
        f32x4 an[4];
        if (ks < 31) {
            const int ko = (ks + 1) << 5;
            #pragma unroll
            for (int r = 0; r < 4; ++r) an[r] = *(const f32x4*)(Ap[r] + ko);
            #pragma unroll
            for (int c = 0; c < 2; ++c) gload_lds16(Bp[c] + ko, sBn + bdst[c]);
        }
        short8 af[4], bf[4];
        #pragma unroll
        for (int m = 0; m < 4; ++m)
            af[m] = *(const short8*)(sAc + lds_off((wr << 6) + (m << 4) + lrow, lk << 3));
        #pragma unroll
        for (int n = 0; n < 4; ++n)
            bf[n] = *(const short8*)(sBc + lds_off((wc << 6) + (n << 4) + lrow, lk << 3));
        #pragma unroll
        for (int m = 0; m < 4; ++m)
            #pragma unroll
            for (int n = 0; n < 4; ++n)
                acc[m][n] = __builtin_amdgcn_mfma_f32_16x16x32_bf16(af[m], bf[n], acc[m][n], 0, 0, 0);
        if (ks < 31) {
            #pragma unroll
            for (int r = 0; r < 4; ++r)
                *(unsigned long long*)(sAn + aoff[r]) = pack4bf(an[r]);
        }
        __syncthreads();
        char* t;
        t = sAc; sAc = sAn; sAn = t;
        t = sBc; sBc = sBn; sBn = t;
    }
}

// ---------- big fused kernel: visual_attn + attention + alpha (partial) ----------
// XCD-bijective swizzle (1568 = 8*196): wk = (j&7)*196 + (j>>3), then n4 = wk&3
// fastest -> the 4 A-tile sharers run temporally adjacent on the SAME XCD,
// so A-tile re-reads hit that XCD's L2 (R4: FETCH 404 -> 112 MB, proven).
__global__ __launch_bounds__(256, 4) void attn_alpha_kernel(
    const float* __restrict__ spatial,          // [50176][1024] fp32
    const unsigned short* __restrict__ WvT,     // [512][1024] bf16
    const float* __restrict__ b_v_att,          // [512]
    const float* __restrict__ hidden_attn,      // [256][512]
    const float* __restrict__ W_alpha,          // [512]
    float* __restrict__ alphap)                 // [4][50176]
{
    __shared__ char sA[2][8192];
    __shared__ char sB[2][8192];
    __shared__ float alpha_s[2][128];
    const int tid = threadIdx.x;
    const int j = blockIdx.x;
    const int wk = (j & 7) * 196 + (j >> 3);
    const int mt = wk >> 2, n4 = wk & 3;
    const int row0 = mt << 7, col0 = n4 << 7;

    f32x4 acc[4][4];
    kloop_dbuf(spatial + (size_t)row0 * 1024, WvT + (size_t)col0 * 1024,
               sA[0], sA[1], sB[0], sB[1], acc, tid);

    const int lane = tid & 63, w = tid >> 6;
    const int wr = w >> 1, wc = w & 1;
    const int lrow = lane & 15, lk = lane >> 4;

    const unsigned bb0 = div196((unsigned)row0);
    const unsigned bb1 = div196((unsigned)(row0 + 127));
    float bv[4], wa[4], h0[4], h1[4];
    #pragma unroll
    for (int n = 0; n < 4; ++n) {
        int g = col0 + (wc << 6) + (n << 4) + lrow;
        bv[n] = b_v_att[g];
        wa[n] = W_alpha[g];
        h0[n] = hidden_attn[bb0 * 512 + g];
        h1[n] = hidden_attn[bb1 * 512 + g];
    }
    // per-wc partial row sums (no atomics: wc slabs are disjoint per wr-half)
    #pragma unroll
    for (int m = 0; m < 4; ++m) {
        #pragma unroll
        for (int i = 0; i < 4; ++i) {
            int rloc = (wr << 6) + (m << 4) + (lk << 2) + i;
            bool first = (div196((unsigned)(row0 + rloc)) == bb0);
            float s = 0.f;
            #pragma unroll
            for (int n = 0; n < 4; ++n) {
                float v = tanh_fast(acc[m][n][i] + bv[n] + (first ? h0[n] : h1[n]));
                s += v * wa[n];
            }
            #pragma unroll
            for (int off = 1; off < 16; off <<= 1) s += __shfl_xor(s, off);
            if (lrow == 0) alpha_s[wc][rloc] = s;
        }
    }
    __syncthreads();
    if (tid < 128)
        alphap[(size_t)n4 * MROWS + row0 + tid] = alpha_s[0][tid] + alpha_s[1][tid];
}

// ---------- small GEMM pair: C = act(A @ BT^T + bias), M=256, K=1024 ----------
struct GemmDesc { const float* A; const unsigned short* BT; const float* bias; float* C; int N; int act; };
struct GemmPair { GemmDesc d[2]; };

__global__ __launch_bounds__(256, 4) void gemm_pair_kernel(GemmPair p)
{
    GemmDesc d = p.d[blockIdx.z];
    __shared__ char sA[2][8192];
    __shared__ char sB[2][8192];
    const int tid = threadIdx.x;
    const int row0 = blockIdx.x << 7;
    const int col0 = blockIdx.y << 7;
    f32x4 acc[4][4];
    kloop_dbuf(d.A + (size_t)row0 * 1024, d.BT + (size_t)col0 * 1024,
               sA[0], sA[1], sB[0], sB[1], acc, tid);
    const int lane = tid & 63, w = tid >> 6;
    const int wr = w >> 1, wc = w & 1;
    const int lrow = lane & 15, lk = lane >> 4;
    #pragma unroll
    for (int n = 0; n < 4; ++n) {
        int col = col0 + (wc << 6) + (n << 4) + lrow;
        float bs = d.bias[col];
        #pragma unroll
        for (int m = 0; m < 4; ++m) {
            int rbase = row0 + (wr << 6) + (m << 4) + (lk << 2);
            #pragma unroll
            for (int i = 0; i < 4; ++i) {
                float v = acc[m][n][i] + bs;
                if (d.act == 1) v = fmaxf(v, 0.f);
                if (d.act == 2) v = tanh_fast(v);
                d.C[(size_t)(rbase + i) * d.N + col] = v;
            }
        }
    }
}

// ---------- batched W transpose + fp32->bf16: src[K][N] -> dst[N][K] ----------
struct TransDesc { const float* src; unsigned short* dst; int K; int N; };
struct TransArgs { TransDesc d[6]; };

__global__ void transpose_cvt_kernel(TransArgs args) {
    TransDesc d = args.d[blockIdx.y];
    int nt = d.N >> 5;
    int tiles = (d.K >> 5) * nt;
    if ((int)blockIdx.x >= tiles) return;
    int tk = blockIdx.x / nt, tn = blockIdx.x % nt;
    __shared__ unsigned short tile[32][33];
    int tx = threadIdx.x & 31, ty = threadIdx.x >> 5;
    int k0 = tk << 5, n0 = tn << 5;
    #pragma unroll
    for (int j = 0; j < 4; ++j)
        tile[ty + j * 8][tx] = f2bf(d.src[(size_t)(k0 + ty + j * 8) * d.N + n0 + tx]);
    __syncthreads();
    #pragma unroll
    for (int j = 0; j < 4; ++j)
        d.dst[(size_t)(n0 + ty + j * 8) * d.K + k0 + tx] = tile[tx][ty + j * 8];
}

// ---------- sentinel alpha + softmax over 197 ----------
__global__ void softmax_sentinel_kernel(
    const float* __restrict__ alphap,   // [4][50176]
    const float* __restrict__ sen_att, const float* __restrict__ hid_att,
    const float* __restrict__ W_alpha,
    float* __restrict__ att, float* __restrict__ beta)
{
    int b = blockIdx.x, tid = threadIdx.x;   // 256 threads
    __shared__ float al[197];
    __shared__ float red[4];
    if (tid < 196) {
        size_t g = (size_t)b * 196 + tid;
        al[tid] = alphap[g] + alphap[MROWS + g] + alphap[2 * MROWS + g] + alphap[3 * MROWS + g];
    }
    float s = 0.f;
    for (int a = tid; a < 512; a += 256)
        s += tanh_fast(sen_att[b * 512 + a] + hid_att[b * 512 + a]) * W_alpha[a];
    #pragma unroll
    for (int off = 1; off < 64; off <<= 1) s += __shfl_xor(s, off);
    if ((tid & 63) == 0) red[tid >> 6] = s;
    __syncthreads();
    if (tid == 0) al[196] = red[0] + red[1] + red[2] + red[3];
    __syncthreads();
    if (tid < 64) {
        float v[4];
        float mx = -1e30f;
        #pragma unroll
        for (int jj = 0; jj < 4; ++jj) {
            int i = tid + jj * 64;
            v[jj] = (i < 197) ? al[i] : -1e30f;
            mx = fmaxf(mx, v[jj]);
        }
        #pragma unroll
        for (int off = 1; off < 64; off <<= 1) mx = fmaxf(mx, __shfl_xor(mx, off));
        float sm = 0.f;
        #pragma unroll
        for (int jj = 0; jj < 4; ++jj) {
            v[jj] = __builtin_amdgcn_exp2f((v[jj] - mx) * 1.442695040888963f);
            if (tid + jj * 64 >= 197) v[jj] = 0.f;
            sm += v[jj];
        }
        #pragma unroll
        for (int off = 1; off < 64; off <<= 1) sm += __shfl_xor(sm, off);
        float inv = 1.f / sm;
        #pragma unroll
        for (int jj = 0; jj < 4; ++jj) {
            int i = tid + jj * 64;
            if (i < 197) {
                float wv = v[jj] * inv;
                att[b * 197 + i] = wv;
                if (i == 196) beta[b] = wv;
            }
        }
    }
}

// ---------- context: ctxh = sum_p w_p * feat_p + w196*sen + hidden_affine ----------
__global__ __launch_bounds__(256) void context_kernel(
    const float* __restrict__ spatial, const float* __restrict__ sen_aff,
    const float* __restrict__ hid_aff, const float* __restrict__ att,
    float* __restrict__ ctxh)
{
    int b = blockIdx.x, half = blockIdx.y, t = threadIdx.x;  // 256 thr, float2
    __shared__ float wsm[197];
    if (t < 197) wsm[t] = att[b * 197 + t];
    __syncthreads();
    int h2 = (half << 8) + t;
    const float2* sp = (const float2*)(spatial + (size_t)b * 196 * 1024) + h2;
    float ax = 0.f, ay = 0.f;
    #pragma unroll 8
    for (int p = 0; p < 196; ++p) {
        float2 x = sp[(size_t)p * 512];
        ax += wsm[p] * x.x; ay += wsm[p] * x.y;
    }
    float w196 = wsm[196];
    float2 sa = ((const float2*)(sen_aff + (size_t)b * 1024))[h2];
    float2 ha = ((const float2*)(hid_aff + (size_t)b * 1024))[h2];
    ctxh[(size_t)b * 1024 + 2 * h2]     = ax + w196 * sa.x + ha.x;
    ctxh[(size_t)b * 1024 + 2 * h2 + 1] = ay + w196 * sa.y + ha.y;
}

// ---------- launch ----------
extern "C" void kernel_launch(void* const* d_in, const int* in_sizes, int n_in,
                              void* d_out, int out_size, void* d_ws, size_t ws_size,
                              hipStream_t stream)
{
    const float* spatial   = (const float*)d_in[0];
    const float* decoder   = (const float*)d_in[1];
    const float* st        = (const float*)d_in[2];
    const float* W_sen_aff = (const float*)d_in[3];
    const float* b_sen_aff = (const float*)d_in[4];
    const float* W_sen_att = (const float*)d_in[5];
    const float* b_sen_att = (const float*)d_in[6];
    const float* W_h_aff   = (const float*)d_in[7];
    const float* b_h_aff   = (const float*)d_in[8];
    const float* W_h_att   = (const float*)d_in[9];
    const float* b_h_att   = (const float*)d_in[10];
    const float* W_v_att   = (const float*)d_in[11];
    const float* b_v_att   = (const float*)d_in[12];
    const float* W_alpha   = (const float*)d_in[13];
    // d_in[14] = b_alpha: cancels in softmax, unused
    const float* W_ctx     = (const float*)d_in[15];
    const float* b_ctx     = (const float*)d_in[16];

    char* ws = (char*)d_ws;
    size_t off = 0;
    auto alloc = [&](size_t bytes) {
        char* p = ws + off; off += (bytes + 255) & ~(size_t)255; return p;
    };
    unsigned short* WvT  = (unsigned short*)alloc((size_t)512 * 1024 * 2);
    unsigned short* WsaT = (unsigned short*)alloc((size_t)1024 * 1024 * 2);
    unsigned short* WstT = (unsigned short*)alloc((size_t)512 * 1024 * 2);
    unsigned short* WhaT = (unsigned short*)alloc((size_t)1024 * 1024 * 2);
    unsigned short* WhtT = (unsigned short*)alloc((size_t)512 * 1024 * 2);
    unsigned short* WcxT = (unsigned short*)alloc((size_t)1024 * 1024 * 2);
    float* sen_aff = (float*)alloc((size_t)256 * 1024 * 4);
    float* sen_att = (float*)alloc((size_t)256 * 512 * 4);
    float* hid_aff = (float*)alloc((size_t)256 * 1024 * 4);
    float* hid_att = (float*)alloc((size_t)256 * 512 * 4);
    float* alphap  = (float*)alloc((size_t)4 * MROWS * 4);
    float* ctxh    = (float*)alloc((size_t)256 * 1024 * 4);

    float* out_l    = (float*)d_out;              // 256*1024
    float* out_att  = out_l + 256 * 1024;         // 256*197
    float* out_beta = out_att + 256 * 197;        // 256

    TransArgs ta;
    ta.d[0] = { W_v_att,   WvT,  1024, 512  };
    ta.d[1] = { W_sen_aff, WsaT, 1024, 1024 };
    ta.d[2] = { W_sen_att, WstT, 1024, 512  };
    ta.d[3] = { W_h_aff,   WhaT, 1024, 1024 };
    ta.d[4] = { W_h_att,   WhtT, 1024, 512  };
    ta.d[5] = { W_ctx,     WcxT, 1024, 1024 };
    transpose_cvt_kernel<<<dim3(1024, 6), 256, 0, stream>>>(ta);

    GemmPair p1;
    p1.d[0] = { st,      WsaT, b_sen_aff, sen_aff, 1024, 1 };
    p1.d[1] = { decoder, WhaT, b_h_aff,   hid_aff, 1024, 2 };
    gemm_pair_kernel<<<dim3(2, 8, 2), 256, 0, stream>>>(p1);

    GemmPair p2;
    p2.d[0] = { sen_aff, WstT, b_sen_att, sen_att, 512, 0 };
    p2.d[1] = { hid_aff, WhtT, b_h_att,   hid_att, 512, 0 };
    gemm_pair_kernel<<<dim3(2, 4, 2), 256, 0, stream>>>(p2);

    attn_alpha_kernel<<<1568, 256, 0, stream>>>(spatial, WvT, b_v_att, hid_att, W_alpha, alphap);
    softmax_sentinel_kernel<<<256, 256, 0, stream>>>(alphap, sen_att, hid_att, W_alpha, out_att, out_beta);
    context_kernel<<<dim3(256, 2), 256, 0, stream>>>(spatial, sen_aff, hid_aff, out_att, ctxh);

    GemmPair p3;
    p3.d[0] = { ctxh, WcxT, b_ctx, out_l, 1024, 2 };
    p3.d[1] = { ctxh, WcxT, b_ctx, out_l, 1024, 2 };
    gemm_pair_kernel<<<dim3(2, 8, 1), 256, 0, stream>>>(p3);
}